// Round 1
// baseline (430.141 us; speedup 1.0000x reference)
//
#include <hip/hip_runtime.h>
#include <math.h>

typedef __attribute__((ext_vector_type(4))) float  floatx4;
typedef __attribute__((ext_vector_type(8))) short  shortx8;
typedef unsigned short ushort_t;
typedef unsigned int   uint32;

#define BB 16
#define LL 4096
#define DD 512
#define SS 64
#define NTOK (BB*LL)       // 65536
#define NCH 64             // scan chunks per sequence
#define CLEN 64            // timesteps per chunk

// ---------- helpers ----------
__device__ __forceinline__ ushort_t f2bf(float f) {
    uint32 u = __float_as_uint(f);
    u += 0x7FFFu + ((u >> 16) & 1u);   // round-to-nearest-even
    return (ushort_t)(u >> 16);
}

// ---------- K0: weight conversion + flag clear ----------
__global__ __launch_bounds__(256) void k_prep(
    const float* __restrict__ Wdt, const float* __restrict__ WB,
    const float* __restrict__ WC,  const float* __restrict__ Wx,
    const float* __restrict__ Wout,
    ushort_t* __restrict__ wcat, ushort_t* __restrict__ woutb, int* __restrict__ flag)
{
    int tid = blockIdx.x * 256 + threadIdx.x;      // 0..131071
    if (tid == 0) *flag = 0;
    int n = tid >> 9, k = tid & 511;
    const float* src = (n < 64) ? Wdt : (n < 128) ? WB : (n < 192) ? WC : Wx;
    wcat[tid] = f2bf(src[(n & 63) * 512 + k]);
    if (tid < 512 * 64) woutb[tid] = f2bf(Wout[tid]);
}

// ---------- K1: LayerNorm + fused 4-way projection + elementwise ----------
// block: 256 thr (4 waves), 64 tokens per block, N=256 outputs, K=512
__global__ __launch_bounds__(256) void k_ln_proj(
    const float* __restrict__ x, const float* __restrict__ lnw, const float* __restrict__ lnb,
    const ushort_t* __restrict__ wcat,
    const float* __restrict__ bdt, const float* __restrict__ bx_, const float* __restrict__ A_log,
    float* __restrict__ Ap, float* __restrict__ BXv, float* __restrict__ Ct)
{
    __shared__ float sMean[64], sRstd[64];
    __shared__ __align__(16) char sBuf[66560];
    ushort_t* sA = (ushort_t*)sBuf;          // [64][72] bf16 x_norm chunk
    ushort_t* sB = sA + 64 * 72;             // [256][72] bf16 Wcat chunk
    float*    sOut = (float*)sBuf;           // [64][260] f32 GEMM out (aliases sA/sB)

    const int tid  = threadIdx.x;
    const int wave = tid >> 6, lane = tid & 63;
    const int ln   = lane & 15, qd = lane >> 4;
    const int token0 = blockIdx.x * 64;

    // ---- phase 1: LN stats (wave w handles tokens w*16..w*16+15) ----
    for (int i = 0; i < 16; i++) {
        int tok = wave * 16 + i;
        const float4* xr = (const float4*)(x + (size_t)(token0 + tok) * DD);
        float4 a = xr[lane];
        float4 b = xr[64 + lane];
        float s = a.x + a.y + a.z + a.w + b.x + b.y + b.z + b.w;
        float q = a.x*a.x + a.y*a.y + a.z*a.z + a.w*a.w
                + b.x*b.x + b.y*b.y + b.z*b.z + b.w*b.w;
        #pragma unroll
        for (int off = 32; off > 0; off >>= 1) {
            s += __shfl_xor(s, off);
            q += __shfl_xor(q, off);
        }
        if (lane == 0) {
            float mu  = s * (1.0f / 512.0f);
            float var = q * (1.0f / 512.0f) - mu * mu;
            sMean[tok] = mu;
            sRstd[tok] = rsqrtf(var + 1e-5f);
        }
    }
    __syncthreads();

    floatx4 acc[4][4] = {};

    // ---- phase 2: K-chunked GEMM ----
    for (int kc = 0; kc < 8; kc++) {
        // stage A: 64 tokens x 64 k, normalize f32 -> bf16
        {
            int q = tid & 15, tr = tid >> 4;
            #pragma unroll
            for (int it = 0; it < 4; it++) {
                int tok = it * 16 + tr;
                float mu = sMean[tok], rs = sRstd[tok];
                float4 v  = *(const float4*)(x + (size_t)(token0 + tok) * DD + kc * 64 + q * 4);
                float4 w4 = *(const float4*)(lnw + kc * 64 + q * 4);
                float4 b4 = *(const float4*)(lnb + kc * 64 + q * 4);
                uint32 lo = (uint32)f2bf((v.x - mu) * rs * w4.x + b4.x)
                          | ((uint32)f2bf((v.y - mu) * rs * w4.y + b4.y) << 16);
                uint32 hi = (uint32)f2bf((v.z - mu) * rs * w4.z + b4.z)
                          | ((uint32)f2bf((v.w - mu) * rs * w4.w + b4.w) << 16);
                uint2 pk; pk.x = lo; pk.y = hi;
                *(uint2*)&sA[tok * 72 + q * 4] = pk;
            }
        }
        // stage B: 256 rows x 64 k bf16
        {
            #pragma unroll
            for (int it = 0; it < 8; it++) {
                int f = it * 256 + tid;
                int n = f >> 3, c8 = f & 7;
                uint4 v = *(const uint4*)(wcat + n * 512 + kc * 64 + c8 * 8);
                *(uint4*)&sB[n * 72 + c8 * 8] = v;
            }
        }
        __syncthreads();
        // MFMA: wave w owns n-range [w*64, w*64+64)
        #pragma unroll
        for (int ks = 0; ks < 64; ks += 32) {
            shortx8 af[4], bf[4];
            #pragma unroll
            for (int mt = 0; mt < 4; mt++)
                af[mt] = *(const shortx8*)&sA[(mt * 16 + ln) * 72 + ks + qd * 8];
            #pragma unroll
            for (int nt = 0; nt < 4; nt++)
                bf[nt] = *(const shortx8*)&sB[(wave * 64 + nt * 16 + ln) * 72 + ks + qd * 8];
            #pragma unroll
            for (int mt = 0; mt < 4; mt++)
                #pragma unroll
                for (int nt = 0; nt < 4; nt++)
                    acc[mt][nt] = __builtin_amdgcn_mfma_f32_16x16x32_bf16(
                        af[mt], bf[nt], acc[mt][nt], 0, 0, 0);
        }
        __syncthreads();
    }

    // ---- write acc -> sOut (C/D layout: col=lane&15, row=quad*4+reg) ----
    #pragma unroll
    for (int mt = 0; mt < 4; mt++)
        #pragma unroll
        for (int nt = 0; nt < 4; nt++)
            #pragma unroll
            for (int r = 0; r < 4; r++) {
                int m = mt * 16 + qd * 4 + r;
                int n = wave * 64 + nt * 16 + ln;
                sOut[m * 260 + n] = acc[mt][nt][r];
            }
    __syncthreads();

    // ---- elementwise epilogue ----
    {
        int s = tid & 63;
        float bdt_s = bdt[s], bx_s = bx_[s];
        float A_s = -expf(A_log[s]);
        #pragma unroll
        for (int i = 0; i < 16; i++) {
            int tok = (tid >> 6) + i * 4;
            float zdt = sOut[tok * 260 + s];
            float zb  = sOut[tok * 260 + 64 + s];
            float zc  = sOut[tok * 260 + 128 + s];
            float zx  = sOut[tok * 260 + 192 + s];
            float zin = zdt + bdt_s;
            float sp  = fmaxf(zin, 0.0f) + log1pf(expf(-fabsf(zin)));   // softplus
            float delta = sp * 0.01f + 1e-4f;
            float dA    = fminf(fmaxf(delta * A_s, -10.0f), -1e-4f);
            float Adisc = expf(dA);
            float a     = fminf(fmaxf(Adisc, 0.001f), 0.999f) + 1e-10f;
            float xp    = zx + bx_s;
            float bxv   = delta * zb * xp;
            size_t g = (size_t)(token0 + tok) * 64 + s;
            Ap[g] = a; BXv[g] = bxv; Ct[g] = zc;
        }
    }
}

// ---------- scan: h[0]=BX[0];  h[t] = a[t]*(h[t-1] + BX[t])  (t>=1) ----------
// uniform affine form: h = alpha*h + beta with alpha=(t==0?0:a), beta=(t==0?bx:a*bx)

// K2a: per-chunk affine summary (A_c, B_c)
__global__ __launch_bounds__(64) void k_scan_a(
    const float* __restrict__ Ap, const float* __restrict__ BXv,
    float* __restrict__ Asum, float* __restrict__ Bsum)
{
    int blk = blockIdx.x;
    int b = blk >> 6, c = blk & 63;
    int s = threadIdx.x;
    size_t base = ((size_t)b * LL + c * CLEN) * 64 + s;
    float A_loc = 1.f, B_loc = 0.f;
    bool fc = (c == 0);
    #pragma unroll 8
    for (int tt = 0; tt < CLEN; tt++) {
        float a = Ap[base + (size_t)tt * 64];
        float v = BXv[base + (size_t)tt * 64];
        float alpha = (fc && tt == 0) ? 0.f : a;
        float beta  = (fc && tt == 0) ? v   : a * v;
        A_loc *= alpha;
        B_loc = fmaf(alpha, B_loc, beta);
    }
    int o = (b * NCH + c) * 64 + s;
    Asum[o] = A_loc; Bsum[o] = B_loc;
}

// K2b: sequential combine across chunks -> h entering each chunk
__global__ __launch_bounds__(64) void k_scan_b(
    const float* __restrict__ Asum, const float* __restrict__ Bsum, float* __restrict__ Hin)
{
    int b = blockIdx.x, s = threadIdx.x;
    float h = 0.f;
    for (int tile = 0; tile < 4; tile++) {
        float rA[16], rB[16];
        #pragma unroll
        for (int cc = 0; cc < 16; cc++) {
            int o = (b * NCH + tile * 16 + cc) * 64 + s;
            rA[cc] = Asum[o]; rB[cc] = Bsum[o];
        }
        #pragma unroll
        for (int cc = 0; cc < 16; cc++) {
            int o = (b * NCH + tile * 16 + cc) * 64 + s;
            Hin[o] = h;
            h = fmaf(rA[cc], h, rB[cc]);
        }
    }
}

// K2c: replay chunk with真 prefix, emit P = C_t * h, finite check
__global__ __launch_bounds__(64) void k_scan_c(
    const float* __restrict__ Ap, const float* __restrict__ BXv, const float* __restrict__ Ct,
    const float* __restrict__ Hin, float* __restrict__ P, int* __restrict__ flag)
{
    int blk = blockIdx.x;
    int b = blk >> 6, c = blk & 63;
    int s = threadIdx.x;
    size_t base = ((size_t)b * LL + c * CLEN) * 64 + s;
    float h = Hin[(b * NCH + c) * 64 + s];
    bool fc = (c == 0);
    int bad = 0;
    #pragma unroll 8
    for (int tt = 0; tt < CLEN; tt++) {
        float a = Ap[base + (size_t)tt * 64];
        float v = BXv[base + (size_t)tt * 64];
        float alpha = (fc && tt == 0) ? 0.f : a;
        float beta  = (fc && tt == 0) ? v   : a * v;
        h = fmaf(alpha, h, beta);
        float p = Ct[base + (size_t)tt * 64] * h;
        if (!__builtin_isfinite(p)) bad = 1;
        P[base + (size_t)tt * 64] = p;
    }
    if (__ballot(bad)) { if (s == 0) atomicOr(flag, 1); }
}

// ---------- K3: out = P @ Wout^T + bout + clip(Dp)*x ----------
// block: 256 thr (4 waves), 32 tokens, N=512 (wave w: d-range w*128), K=64
__global__ __launch_bounds__(256) void k_out(
    const float* __restrict__ P, const ushort_t* __restrict__ woutb,
    const float* __restrict__ bout, const float* __restrict__ Dp,
    const float* __restrict__ x, const int* __restrict__ flag,
    float* __restrict__ out)
{
    __shared__ __align__(16) ushort_t sP[32 * 72];
    const int tid  = threadIdx.x;
    const int wave = tid >> 6, lane = tid & 63;
    const int ln   = lane & 15, qd = lane >> 4;
    const int token0 = blockIdx.x * 32;

    {
        int q = tid & 15, tr = tid >> 4;
        #pragma unroll
        for (int it = 0; it < 2; it++) {
            int tok = it * 16 + tr;
            float4 v = *(const float4*)(P + (size_t)(token0 + tok) * 64 + q * 4);
            uint32 lo = (uint32)f2bf(v.x) | ((uint32)f2bf(v.y) << 16);
            uint32 hi = (uint32)f2bf(v.z) | ((uint32)f2bf(v.w) << 16);
            uint2 pk; pk.x = lo; pk.y = hi;
            *(uint2*)&sP[tok * 72 + q * 4] = pk;
        }
    }
    float fmul = (*flag) ? 0.0f : 1.0f;
    __syncthreads();

    floatx4 acc[2][8] = {};
    const int d0 = wave * 128;
    #pragma unroll
    for (int ks = 0; ks < 64; ks += 32) {
        shortx8 af0 = *(const shortx8*)&sP[(ln) * 72 + ks + qd * 8];
        shortx8 af1 = *(const shortx8*)&sP[(16 + ln) * 72 + ks + qd * 8];
        #pragma unroll
        for (int nt = 0; nt < 8; nt++) {
            shortx8 bf = *(const shortx8*)(woutb + (size_t)(d0 + nt * 16 + ln) * 64 + ks + qd * 8);
            acc[0][nt] = __builtin_amdgcn_mfma_f32_16x16x32_bf16(af0, bf, acc[0][nt], 0, 0, 0);
            acc[1][nt] = __builtin_amdgcn_mfma_f32_16x16x32_bf16(af1, bf, acc[1][nt], 0, 0, 0);
        }
    }

    #pragma unroll
    for (int nt = 0; nt < 8; nt++) {
        int d = d0 + nt * 16 + ln;
        float bo = bout[d];
        float dp = fminf(fmaxf(Dp[d], -2.f), 2.f);
        #pragma unroll
        for (int mt = 0; mt < 2; mt++)
            #pragma unroll
            for (int r = 0; r < 4; r++) {
                int tok = token0 + mt * 16 + qd * 4 + r;
                size_t g = (size_t)tok * DD + d;
                out[g] = fmaf(acc[mt][nt][r], fmul, fmaf(dp, x[g], bo));
            }
    }
}

// ---------- launch ----------
extern "C" void kernel_launch(void* const* d_in, const int* in_sizes, int n_in,
                              void* d_out, int out_size, void* d_ws, size_t ws_size,
                              hipStream_t stream)
{
    const float* x     = (const float*)d_in[0];
    const float* lnw   = (const float*)d_in[1];
    const float* lnb   = (const float*)d_in[2];
    const float* Wx    = (const float*)d_in[3];
    const float* bx_   = (const float*)d_in[4];
    const float* Wdt   = (const float*)d_in[5];
    const float* bdt   = (const float*)d_in[6];
    const float* A_log = (const float*)d_in[7];
    const float* WB    = (const float*)d_in[8];
    const float* WC    = (const float*)d_in[9];
    const float* Dp    = (const float*)d_in[10];
    const float* Wout  = (const float*)d_in[11];
    const float* bout  = (const float*)d_in[12];
    float* out = (float*)d_out;

    char* w = (char*)d_ws;
    constexpr size_t SZ_T = (size_t)NTOK * 64 * 4;       // 16 MB per (token,s) f32 tensor
    float*    Ap    = (float*)(w);
    float*    BXv   = (float*)(w + SZ_T);
    float*    Ct    = (float*)(w + 2 * SZ_T);
    float*    Pm    = (float*)(w + 3 * SZ_T);
    float*    Asum  = (float*)(w + 4 * SZ_T);
    float*    Bsum  = (float*)(w + 4 * SZ_T + 262144);
    float*    Hin   = (float*)(w + 4 * SZ_T + 2 * 262144);
    ushort_t* Wcat  = (ushort_t*)(w + 4 * SZ_T + 3 * 262144);
    ushort_t* WoutB = (ushort_t*)(w + 4 * SZ_T + 3 * 262144 + 262144);
    int*      flag  = (int*)(w + 4 * SZ_T + 3 * 262144 + 262144 + 65536);

    k_prep<<<512, 256, 0, stream>>>(Wdt, WB, WC, Wx, Wout, Wcat, WoutB, flag);
    k_ln_proj<<<NTOK / 64, 256, 0, stream>>>(x, lnw, lnb, Wcat, bdt, bx_, A_log, Ap, BXv, Ct);
    k_scan_a<<<BB * NCH, 64, 0, stream>>>(Ap, BXv, Asum, Bsum);
    k_scan_b<<<BB, 64, 0, stream>>>(Asum, Bsum, Hin);
    k_scan_c<<<BB * NCH, 64, 0, stream>>>(Ap, BXv, Ct, Hin, Pm, flag);
    k_out<<<NTOK / 32, 256, 0, stream>>>(Pm, WoutB, bout, Dp, x, flag, out);
}

// Round 2
// 341.748 us; speedup vs baseline: 1.2586x; 1.2586x over previous
//
#include <hip/hip_runtime.h>
#include <math.h>

typedef __attribute__((ext_vector_type(4))) float  floatx4;
typedef __attribute__((ext_vector_type(8))) short  shortx8;
typedef unsigned short ushort_t;
typedef unsigned int   uint32;

#define BB 16
#define LL 4096
#define DD 512
#define SS 64
#define NTOK (BB*LL)       // 65536
#define NCH 64             // scan chunks per sequence (64 tokens each)

// ---------- helpers ----------
__device__ __forceinline__ ushort_t f2bf(float f) {
    uint32 u = __float_as_uint(f);
    u += 0x7FFFu + ((u >> 16) & 1u);   // round-to-nearest-even
    return (ushort_t)(u >> 16);
}

// ---------- K0: weight conversion ----------
__global__ __launch_bounds__(256) void k_prep(
    const float* __restrict__ Wdt, const float* __restrict__ WB,
    const float* __restrict__ WC,  const float* __restrict__ Wx,
    const float* __restrict__ Wout,
    ushort_t* __restrict__ wcat, ushort_t* __restrict__ woutb)
{
    int tid = blockIdx.x * 256 + threadIdx.x;      // 0..131071
    int n = tid >> 9, k = tid & 511;
    const float* src = (n < 64) ? Wdt : (n < 128) ? WB : (n < 192) ? WC : Wx;
    wcat[tid] = f2bf(src[(n & 63) * 512 + k]);
    if (tid < 512 * 64) woutb[tid] = f2bf(Wout[tid]);
}

// ---------- K1: LayerNorm + fused 4-way projection + elementwise + chunk scan summary ----------
// block: 256 thr (4 waves), 64 tokens (= one scan chunk), N=256, K=512.
// n-tiling: n = nt*64 + wave*16 + ln  ->  each wave holds all 4 projections for
// s-range [wave*16, wave*16+16), so the elementwise epilogue is per-lane.
__global__ __launch_bounds__(256) void k_ln_proj(
    const float* __restrict__ x, const float* __restrict__ lnw, const float* __restrict__ lnb,
    const ushort_t* __restrict__ wcat,
    const float* __restrict__ bdt, const float* __restrict__ bx_, const float* __restrict__ A_log,
    float* __restrict__ Ap, float* __restrict__ BXv, float* __restrict__ Ct,
    float* __restrict__ Asum, float* __restrict__ Bsum)
{
    __shared__ float sMean[64], sRstd[64];
    __shared__ __align__(16) char sBuf[46080];
    ushort_t* sA = (ushort_t*)sBuf;          // [64][72] bf16 x_norm chunk
    ushort_t* sB = sA + 64 * 72;             // [256][72] bf16 Wcat chunk
    float*    sPA = (float*)sBuf;            // [64 s][17 pad] seg partials (aliases, post-GEMM)
    float*    sPB = sPA + 64 * 17;

    const int tid  = threadIdx.x;
    const int wave = tid >> 6, lane = tid & 63;
    const int ln   = lane & 15, qd = lane >> 4;
    const int token0 = blockIdx.x * 64;

    // ---- phase 1: LN stats ----
    for (int i = 0; i < 16; i++) {
        int tok = wave * 16 + i;
        const float4* xr = (const float4*)(x + (size_t)(token0 + tok) * DD);
        float4 a = xr[lane];
        float4 b = xr[64 + lane];
        float s = a.x + a.y + a.z + a.w + b.x + b.y + b.z + b.w;
        float q = a.x*a.x + a.y*a.y + a.z*a.z + a.w*a.w
                + b.x*b.x + b.y*b.y + b.z*b.z + b.w*b.w;
        #pragma unroll
        for (int off = 32; off > 0; off >>= 1) {
            s += __shfl_xor(s, off);
            q += __shfl_xor(q, off);
        }
        if (lane == 0) {
            float mu  = s * (1.0f / 512.0f);
            float var = q * (1.0f / 512.0f) - mu * mu;
            sMean[tok] = mu;
            sRstd[tok] = rsqrtf(var + 1e-5f);
        }
    }
    __syncthreads();

    floatx4 acc[4][4] = {};

    // ---- phase 2: K-chunked GEMM ----
    for (int kc = 0; kc < 8; kc++) {
        {   // stage A: 64 tokens x 64 k, normalize f32 -> bf16
            int q = tid & 15, tr = tid >> 4;
            #pragma unroll
            for (int it = 0; it < 4; it++) {
                int tok = it * 16 + tr;
                float mu = sMean[tok], rs = sRstd[tok];
                float4 v  = *(const float4*)(x + (size_t)(token0 + tok) * DD + kc * 64 + q * 4);
                float4 w4 = *(const float4*)(lnw + kc * 64 + q * 4);
                float4 b4 = *(const float4*)(lnb + kc * 64 + q * 4);
                uint32 lo = (uint32)f2bf((v.x - mu) * rs * w4.x + b4.x)
                          | ((uint32)f2bf((v.y - mu) * rs * w4.y + b4.y) << 16);
                uint32 hi = (uint32)f2bf((v.z - mu) * rs * w4.z + b4.z)
                          | ((uint32)f2bf((v.w - mu) * rs * w4.w + b4.w) << 16);
                uint2 pk; pk.x = lo; pk.y = hi;
                *(uint2*)&sA[tok * 72 + q * 4] = pk;
            }
        }
        {   // stage B: 256 rows x 64 k bf16
            #pragma unroll
            for (int it = 0; it < 8; it++) {
                int f = it * 256 + tid;
                int n = f >> 3, c8 = f & 7;
                uint4 v = *(const uint4*)(wcat + n * 512 + kc * 64 + c8 * 8);
                *(uint4*)&sB[n * 72 + c8 * 8] = v;
            }
        }
        __syncthreads();
        #pragma unroll
        for (int ks = 0; ks < 64; ks += 32) {
            shortx8 af[4], bf[4];
            #pragma unroll
            for (int mt = 0; mt < 4; mt++)
                af[mt] = *(const shortx8*)&sA[(mt * 16 + ln) * 72 + ks + qd * 8];
            #pragma unroll
            for (int nt = 0; nt < 4; nt++)
                bf[nt] = *(const shortx8*)&sB[(nt * 64 + wave * 16 + ln) * 72 + ks + qd * 8];
            #pragma unroll
            for (int mt = 0; mt < 4; mt++)
                #pragma unroll
                for (int nt = 0; nt < 4; nt++)
                    acc[mt][nt] = __builtin_amdgcn_mfma_f32_16x16x32_bf16(
                        af[mt], bf[nt], acc[mt][nt], 0, 0, 0);
        }
        __syncthreads();   // last iter: also guards sBuf reuse as sPA/sPB
    }

    // ---- per-lane elementwise epilogue + segment affine partials ----
    // lane owns s = wave*16+ln, tokens {mt*16 + qd*4 + r}. C/D: col=lane&15, row=qd*4+r.
    {
        int s = wave * 16 + ln;
        float bdt_s = bdt[s], bx_s = bx_[s];
        float A_s = -expf(A_log[s]);
        bool fc = ((blockIdx.x & 63) == 0);
        #pragma unroll
        for (int mt = 0; mt < 4; mt++) {
            float Al = 1.f, Bl = 0.f;
            #pragma unroll
            for (int r = 0; r < 4; r++) {
                int tok = mt * 16 + qd * 4 + r;
                float zdt = acc[mt][0][r];
                float zb  = acc[mt][1][r];
                float zc  = acc[mt][2][r];
                float zx  = acc[mt][3][r];
                float zin = zdt + bdt_s;
                float sp  = fmaxf(zin, 0.0f) + log1pf(expf(-fabsf(zin)));   // softplus
                float delta = sp * 0.01f + 1e-4f;
                float dA    = fminf(fmaxf(delta * A_s, -10.0f), -1e-4f);
                float Adisc = expf(dA);
                float a     = fminf(fmaxf(Adisc, 0.001f), 0.999f) + 1e-10f;
                float bxv   = delta * zb * (zx + bx_s);
                size_t g = (size_t)(token0 + tok) * 64 + s;
                Ap[g] = a; BXv[g] = bxv; Ct[g] = zc;
                bool first = fc && (tok == 0);
                float alpha = first ? 0.f : a;
                float beta  = first ? bxv : a * bxv;
                Al *= alpha;
                Bl = fmaf(alpha, Bl, beta);
            }
            // segment index seg = mt*4+qd covers tokens [seg*4, seg*4+4)
            sPA[s * 17 + mt * 4 + qd] = Al;
            sPB[s * 17 + mt * 4 + qd] = Bl;
        }
    }
    __syncthreads();
    if (tid < 64) {   // fold 16 segments (token order) -> chunk summary
        float A = sPA[tid * 17 + 0], B = sPB[tid * 17 + 0];
        #pragma unroll
        for (int g = 1; g < 16; g++) {
            float pa = sPA[tid * 17 + g], pb = sPB[tid * 17 + g];
            A *= pa;
            B = fmaf(pa, B, pb);
        }
        int o = blockIdx.x * 64 + tid;
        Asum[o] = A; Bsum[o] = B;
    }
}

// ---------- K2: sequential combine across chunks -> h entering each chunk ----------
__global__ __launch_bounds__(64) void k_scan_b(
    const float* __restrict__ Asum, const float* __restrict__ Bsum, float* __restrict__ Hin)
{
    int b = blockIdx.x, s = threadIdx.x;
    float h = 0.f;
    for (int tile = 0; tile < 4; tile++) {
        float rA[16], rB[16];
        #pragma unroll
        for (int cc = 0; cc < 16; cc++) {
            int o = (b * NCH + tile * 16 + cc) * 64 + s;
            rA[cc] = Asum[o]; rB[cc] = Bsum[o];
        }
        #pragma unroll
        for (int cc = 0; cc < 16; cc++) {
            int o = (b * NCH + tile * 16 + cc) * 64 + s;
            Hin[o] = h;
            h = fmaf(rA[cc], h, rB[cc]);
        }
    }
}

// ---------- K3: fused scan replay + out GEMM + residual ----------
// block: 512 thr (8 waves), one 64-token chunk; N=512 (wave w: d-range w*64), K=64
__global__ __launch_bounds__(512, 4) void k_out2(
    const float* __restrict__ Ap, const float* __restrict__ BXv, const float* __restrict__ Ct,
    const float* __restrict__ Hin, const ushort_t* __restrict__ woutb,
    const float* __restrict__ bout, const float* __restrict__ Dp,
    const float* __restrict__ x, float* __restrict__ out)
{
    __shared__ __align__(16) char buf[33024];
    ushort_t* sP   = (ushort_t*)buf;              // [64 tok][72] bf16 P
    float*    sSA  = (float*)(buf + 9216);        // [8 seg][64 s]
    float*    sSB  = (float*)(buf + 9216 + 2048); // [8 seg][64 s]
    float*    sOut = (float*)buf;                 // [16][516] f32 (aliases all, post-GEMM)

    const int tid  = threadIdx.x;
    const int wave = tid >> 6, lane = tid & 63;
    const int ln   = lane & 15, qd = lane >> 4;
    const int blk  = blockIdx.x;
    const int token0 = blk * 64;
    const bool fc = ((blk & 63) == 0);

    // ---- phase A: replay chunk scan, build P bf16 in sP ----
    {
        const int s = lane, j = wave;              // 8 segments x 8 steps
        size_t gbase = (size_t)token0 * 64 + (size_t)j * 8 * 64 + s;
        float av[8], vv[8];
        #pragma unroll
        for (int i = 0; i < 8; i++) {
            av[i] = Ap[gbase + (size_t)i * 64];
            vv[i] = BXv[gbase + (size_t)i * 64];
        }
        float Al = 1.f, Bl = 0.f;
        #pragma unroll
        for (int i = 0; i < 8; i++) {
            bool first = fc && (j == 0) && (i == 0);
            float alpha = first ? 0.f : av[i];
            float beta  = first ? vv[i] : av[i] * vv[i];
            Al *= alpha;
            Bl = fmaf(alpha, Bl, beta);
        }
        sSA[j * 64 + s] = Al;
        sSB[j * 64 + s] = Bl;
        __syncthreads();
        float h = Hin[blk * 64 + s];
        for (int jj = 0; jj < j; jj++)             // wave-uniform trip count
            h = fmaf(sSA[jj * 64 + s], h, sSB[jj * 64 + s]);
        #pragma unroll
        for (int i = 0; i < 8; i++) {
            bool first = fc && (j == 0) && (i == 0);
            float alpha = first ? 0.f : av[i];
            float beta  = first ? vv[i] : av[i] * vv[i];
            h = fmaf(alpha, h, beta);
            float ct = Ct[gbase + (size_t)i * 64];
            sP[(j * 8 + i) * 72 + s] = f2bf(ct * h);
        }
    }
    __syncthreads();

    // ---- phase B: GEMM 64x512, K=64 ----
    floatx4 acc[4][4] = {};
    const int d0 = wave * 64;
    #pragma unroll
    for (int ks = 0; ks < 64; ks += 32) {
        shortx8 af[4], bf[4];
        #pragma unroll
        for (int mt = 0; mt < 4; mt++)
            af[mt] = *(const shortx8*)&sP[(mt * 16 + ln) * 72 + ks + qd * 8];
        #pragma unroll
        for (int nt = 0; nt < 4; nt++)
            bf[nt] = *(const shortx8*)(woutb + (size_t)(d0 + nt * 16 + ln) * 64 + ks + qd * 8);
        #pragma unroll
        for (int mt = 0; mt < 4; mt++)
            #pragma unroll
            for (int nt = 0; nt < 4; nt++)
                acc[mt][nt] = __builtin_amdgcn_mfma_f32_16x16x32_bf16(
                    af[mt], bf[nt], acc[mt][nt], 0, 0, 0);
    }

    // ---- phase C: transposed epilogue, float4 coalesced ----
    for (int mt = 0; mt < 4; mt++) {
        __syncthreads();                            // mt=0: guards sP reads vs sOut writes
        #pragma unroll
        for (int nt = 0; nt < 4; nt++)
            #pragma unroll
            for (int r = 0; r < 4; r++)
                sOut[(qd * 4 + r) * 516 + d0 + nt * 16 + ln] = acc[mt][nt][r];
        __syncthreads();
        #pragma unroll
        for (int it = 0; it < 4; it++) {
            int idx = it * 512 + tid;
            int row = idx >> 7, c4 = (idx & 127) * 4;
            int tok = token0 + mt * 16 + row;
            float4 o  = *(float4*)&sOut[row * 516 + c4];
            float4 xv = *(const float4*)(x + (size_t)tok * DD + c4);
            float4 bo = *(const float4*)(bout + c4);
            float4 dp = *(const float4*)(Dp + c4);
            float4 res;
            res.x = fmaf(fminf(fmaxf(dp.x, -2.f), 2.f), xv.x, o.x + bo.x);
            res.y = fmaf(fminf(fmaxf(dp.y, -2.f), 2.f), xv.y, o.y + bo.y);
            res.z = fmaf(fminf(fmaxf(dp.z, -2.f), 2.f), xv.z, o.z + bo.z);
            res.w = fmaf(fminf(fmaxf(dp.w, -2.f), 2.f), xv.w, o.w + bo.w);
            *(float4*)(out + (size_t)tok * DD + c4) = res;
        }
    }
}

// ---------- launch ----------
extern "C" void kernel_launch(void* const* d_in, const int* in_sizes, int n_in,
                              void* d_out, int out_size, void* d_ws, size_t ws_size,
                              hipStream_t stream)
{
    const float* x     = (const float*)d_in[0];
    const float* lnw   = (const float*)d_in[1];
    const float* lnb   = (const float*)d_in[2];
    const float* Wx    = (const float*)d_in[3];
    const float* bx_   = (const float*)d_in[4];
    const float* Wdt   = (const float*)d_in[5];
    const float* bdt   = (const float*)d_in[6];
    const float* A_log = (const float*)d_in[7];
    const float* WB    = (const float*)d_in[8];
    const float* WC    = (const float*)d_in[9];
    const float* Dp    = (const float*)d_in[10];
    const float* Wout  = (const float*)d_in[11];
    const float* bout  = (const float*)d_in[12];
    float* out = (float*)d_out;

    char* w = (char*)d_ws;
    constexpr size_t SZ_T = (size_t)NTOK * 64 * 4;       // 16 MB per (token,s) f32 tensor
    float*    Ap    = (float*)(w);
    float*    BXv   = (float*)(w + SZ_T);
    float*    Ct    = (float*)(w + 2 * SZ_T);
    float*    Asum  = (float*)(w + 3 * SZ_T);
    float*    Bsum  = (float*)(w + 3 * SZ_T + 262144);
    float*    Hin   = (float*)(w + 3 * SZ_T + 2 * 262144);
    ushort_t* Wcat  = (ushort_t*)(w + 3 * SZ_T + 3 * 262144);
    ushort_t* WoutB = (ushort_t*)(w + 3 * SZ_T + 3 * 262144 + 262144);

    k_prep<<<512, 256, 0, stream>>>(Wdt, WB, WC, Wx, Wout, Wcat, WoutB);
    k_ln_proj<<<NTOK / 64, 256, 0, stream>>>(x, lnw, lnb, Wcat, bdt, bx_, A_log,
                                             Ap, BXv, Ct, Asum, Bsum);
    k_scan_b<<<BB, 64, 0, stream>>>(Asum, Bsum, Hin);
    k_out2<<<NTOK / 64, 512, 0, stream>>>(Ap, BXv, Ct, Hin, WoutB, bout, Dp, x, out);
}

// Round 3
// 337.492 us; speedup vs baseline: 1.2745x; 1.0126x over previous
//
#include <hip/hip_runtime.h>
#include <math.h>

typedef __attribute__((ext_vector_type(4))) float  floatx4;
typedef __attribute__((ext_vector_type(8))) short  shortx8;
typedef unsigned short ushort_t;
typedef unsigned int   uint32;

#define BB 16
#define LL 4096
#define DD 512
#define SS 64
#define NTOK (BB*LL)       // 65536
#define NCH 64             // scan chunks per sequence (64 tokens each)

// ---------- helpers ----------
__device__ __forceinline__ ushort_t f2bf(float f) {
    uint32 u = __float_as_uint(f);
    u += 0x7FFFu + ((u >> 16) & 1u);   // round-to-nearest-even
    return (ushort_t)(u >> 16);
}

// async global->LDS, 16B per lane. lptr must be wave-uniform; HW adds lane*16.
__device__ __forceinline__ void gload16(const void* g, void* l) {
    __builtin_amdgcn_global_load_lds(
        (const __attribute__((address_space(1))) unsigned int*)g,
        (__attribute__((address_space(3))) unsigned int*)l, 16, 0, 0);
}

// ---------- K0: weight conversion ----------
__global__ __launch_bounds__(256) void k_prep(
    const float* __restrict__ Wdt, const float* __restrict__ WB,
    const float* __restrict__ WC,  const float* __restrict__ Wx,
    const float* __restrict__ Wout,
    ushort_t* __restrict__ wcat, ushort_t* __restrict__ woutb)
{
    int tid = blockIdx.x * 256 + threadIdx.x;      // 0..131071
    int n = tid >> 9, k = tid & 511;
    const float* src = (n < 64) ? Wdt : (n < 128) ? WB : (n < 192) ? WC : Wx;
    wcat[tid] = f2bf(src[(n & 63) * 512 + k]);
    if (tid < 512 * 64) woutb[tid] = f2bf(Wout[tid]);
}

// ---------- K1: LayerNorm -> xn bf16 (pure memory-bound) ----------
// one wave per token: 64 lanes x 8 f32
__global__ __launch_bounds__(256) void k_ln(
    const float* __restrict__ x, const float* __restrict__ lnw, const float* __restrict__ lnb,
    ushort_t* __restrict__ xn)
{
    const int wave = threadIdx.x >> 6, lane = threadIdx.x & 63;
    const int tok = blockIdx.x * 4 + wave;
    const float4* xr = (const float4*)(x + (size_t)tok * DD);
    float4 a = xr[lane * 2], b = xr[lane * 2 + 1];
    float s = a.x + a.y + a.z + a.w + b.x + b.y + b.z + b.w;
    float q = a.x*a.x + a.y*a.y + a.z*a.z + a.w*a.w
            + b.x*b.x + b.y*b.y + b.z*b.z + b.w*b.w;
    #pragma unroll
    for (int off = 32; off > 0; off >>= 1) {
        s += __shfl_xor(s, off);
        q += __shfl_xor(q, off);
    }
    float mu = s * (1.0f / 512.0f);
    float rs = rsqrtf(q * (1.0f / 512.0f) - mu * mu + 1e-5f);
    float4 wa = ((const float4*)lnw)[lane * 2], wb = ((const float4*)lnw)[lane * 2 + 1];
    float4 ba = ((const float4*)lnb)[lane * 2], bb = ((const float4*)lnb)[lane * 2 + 1];
    uint4 pk;
    pk.x = (uint32)f2bf((a.x - mu) * rs * wa.x + ba.x) | ((uint32)f2bf((a.y - mu) * rs * wa.y + ba.y) << 16);
    pk.y = (uint32)f2bf((a.z - mu) * rs * wa.z + ba.z) | ((uint32)f2bf((a.w - mu) * rs * wa.w + ba.w) << 16);
    pk.z = (uint32)f2bf((b.x - mu) * rs * wb.x + bb.x) | ((uint32)f2bf((b.y - mu) * rs * wb.y + bb.y) << 16);
    pk.w = (uint32)f2bf((b.z - mu) * rs * wb.z + bb.z) | ((uint32)f2bf((b.w - mu) * rs * wb.w + bb.w) << 16);
    ((uint4*)(xn + (size_t)tok * DD))[lane] = pk;
}

// ---------- K2: projection GEMM 128x256 K=512 (m97-style) + elementwise + chunk summaries ----------
// 512 thr (8 waves). wave w: mh=w>>2 (64-token half = scan chunk), nq=w&3.
// n-tiling n = nt*64 + nq*16 + ln  -> per-lane epilogue holds all 4 projections for s=nq*16+ln.
// LDS XOR swizzle: element (row, k8) at byte row*128 + ((k8 ^ (row&7))<<4)
__global__ __launch_bounds__(512, 4) void k_proj(
    const ushort_t* __restrict__ xn, const ushort_t* __restrict__ wcat,
    const float* __restrict__ bdt, const float* __restrict__ bx_, const float* __restrict__ A_log,
    float* __restrict__ Ap, float* __restrict__ BXv, float* __restrict__ Ct,
    float* __restrict__ Asum, float* __restrict__ Bsum)
{
    __shared__ __align__(16) char sBuf[49152];
    ushort_t* sA = (ushort_t*)sBuf;              // swizzled [128][64]
    ushort_t* sB = (ushort_t*)(sBuf + 16384);    // swizzled [256][64]
    float*    sPA = (float*)sBuf;                // [2 ch][64 s][17] alias post-GEMM
    float*    sPB = sPA + 2 * 64 * 17;

    const int tid  = threadIdx.x;
    const int wave = tid >> 6, lane = tid & 63;
    const int ln   = lane & 15, qd = lane >> 4;
    const int mh   = wave >> 2, nq = wave & 3;
    const int token0 = blockIdx.x * 128;

    // precompute swizzled staging source coords
    int tA[2], cA[2], tB[4], cB[4];
    #pragma unroll
    for (int r = 0; r < 2; r++) { int sl = r * 512 + tid; tA[r] = sl >> 3; cA[r] = ((sl & 7) ^ (tA[r] & 7)) * 8; }
    #pragma unroll
    for (int r = 0; r < 4; r++) { int sl = r * 512 + tid; tB[r] = sl >> 3; cB[r] = ((sl & 7) ^ (tB[r] & 7)) * 8; }

    floatx4 acc[4][4] = {};

    for (int kc = 0; kc < 8; kc++) {
        const int kb = kc * 64;
        #pragma unroll
        for (int r = 0; r < 2; r++)
            gload16(xn + (size_t)(token0 + tA[r]) * DD + kb + cA[r],
                    sBuf + r * 8192 + wave * 1024);
        #pragma unroll
        for (int r = 0; r < 4; r++)
            gload16(wcat + (size_t)tB[r] * DD + kb + cB[r],
                    sBuf + 16384 + r * 8192 + wave * 1024);
        __syncthreads();
        #pragma unroll
        for (int ks8 = 0; ks8 < 8; ks8 += 4) {
            shortx8 af[4], bf[4];
            #pragma unroll
            for (int mt = 0; mt < 4; mt++) {
                int t = mh * 64 + mt * 16 + ln;
                af[mt] = *(const shortx8*)&sA[t * 64 + (((ks8 + qd) ^ (ln & 7)) << 3)];
            }
            #pragma unroll
            for (int nt = 0; nt < 4; nt++) {
                int n = nt * 64 + nq * 16 + ln;
                bf[nt] = *(const shortx8*)&sB[n * 64 + (((ks8 + qd) ^ (ln & 7)) << 3)];
            }
            #pragma unroll
            for (int mt = 0; mt < 4; mt++)
                #pragma unroll
                for (int nt = 0; nt < 4; nt++)
                    acc[mt][nt] = __builtin_amdgcn_mfma_f32_16x16x32_bf16(
                        af[mt], bf[nt], acc[mt][nt], 0, 0, 0);
        }
        __syncthreads();
    }

    // ---- per-lane elementwise + segment affine partials ----
    {
        const int s = nq * 16 + ln;
        float bdt_s = bdt[s], bx_s = bx_[s];
        float A_s = -expf(A_log[s]);
        const bool fc = ((blockIdx.x & 31) == 0) && (mh == 0);   // first chunk of sequence
        #pragma unroll
        for (int mt = 0; mt < 4; mt++) {
            float Al = 1.f, Bl = 0.f;
            #pragma unroll
            for (int r = 0; r < 4; r++) {
                int tl  = mt * 16 + qd * 4 + r;            // token within chunk
                int tok = token0 + mh * 64 + tl;
                float zdt = acc[mt][0][r];
                float zb  = acc[mt][1][r];
                float zc  = acc[mt][2][r];
                float zx  = acc[mt][3][r];
                float zin = zdt + bdt_s;
                float sp  = fmaxf(zin, 0.0f) + log1pf(expf(-fabsf(zin)));   // softplus
                float delta = sp * 0.01f + 1e-4f;
                float dA    = fminf(fmaxf(delta * A_s, -10.0f), -1e-4f);
                float a     = fminf(fmaxf(expf(dA), 0.001f), 0.999f) + 1e-10f;
                float bxv   = delta * zb * (zx + bx_s);
                size_t g = (size_t)tok * 64 + s;
                Ap[g] = a; BXv[g] = bxv; Ct[g] = zc;
                bool first = fc && (tl == 0);
                float alpha = first ? 0.f : a;
                float beta  = first ? bxv : a * bxv;
                Al *= alpha;
                Bl = fmaf(alpha, Bl, beta);
            }
            sPA[(mh * 64 + s) * 17 + mt * 4 + qd] = Al;
            sPB[(mh * 64 + s) * 17 + mt * 4 + qd] = Bl;
        }
    }
    __syncthreads();
    if (tid < 128) {   // fold 16 segments -> chunk summary (2 chunks per block)
        int ch = tid >> 6, ss = tid & 63;
        const float* pa = &sPA[(ch * 64 + ss) * 17];
        const float* pb = &sPB[(ch * 64 + ss) * 17];
        float A = pa[0], B = pb[0];
        #pragma unroll
        for (int g = 1; g < 16; g++) {
            A *= pa[g];
            B = fmaf(pa[g], B, pb[g]);
        }
        int o = (blockIdx.x * 2 + ch) * 64 + ss;
        Asum[o] = A; Bsum[o] = B;
    }
}

// ---------- K3: chunk-prefix fold + scan replay -> P bf16 ----------
// block: 256 thr (4 waves = 4 consecutive chunks of one sequence)
__global__ __launch_bounds__(256) void k_scan(
    const float* __restrict__ Ap, const float* __restrict__ BXv, const float* __restrict__ Ct,
    const float* __restrict__ Asum, const float* __restrict__ Bsum,
    ushort_t* __restrict__ P)
{
    __shared__ float sAs[4096], sBs[4096];
    const int tid = threadIdx.x;
    const int b = blockIdx.x >> 4, cq = blockIdx.x & 15;
    #pragma unroll
    for (int i = 0; i < 16; i++) {
        int idx = i * 256 + tid;
        sAs[idx] = Asum[b * 4096 + idx];
        sBs[idx] = Bsum[b * 4096 + idx];
    }
    __syncthreads();
    const int w = tid >> 6, s = tid & 63;
    const int c = cq * 4 + w;
    float h = 0.f;
    for (int cc = 0; cc < c; cc++)                 // wave-uniform trip count
        h = fmaf(sAs[cc * 64 + s], h, sBs[cc * 64 + s]);
    size_t base = ((size_t)b * LL + c * 64) * 64 + s;
    const bool fc = (c == 0);
    #pragma unroll 8
    for (int t = 0; t < 64; t++) {
        float a = Ap[base + (size_t)t * 64];
        float v = BXv[base + (size_t)t * 64];
        float alpha = (fc && t == 0) ? 0.f : a;
        float beta  = (fc && t == 0) ? v   : a * v;
        h = fmaf(alpha, h, beta);
        P[base + (size_t)t * 64] = f2bf(Ct[base + (size_t)t * 64] * h);
    }
}

// ---------- K4: out = P @ Wout^T + bout + clip(Dp)*x ----------
// 256 thr (4 waves), tile 64 tok x 256 d (nh = d-half), K=64
__global__ __launch_bounds__(256, 4) void k_gemm2(
    const ushort_t* __restrict__ P, const ushort_t* __restrict__ woutb,
    const float* __restrict__ bout, const float* __restrict__ Dp,
    const float* __restrict__ x, float* __restrict__ out)
{
    __shared__ __align__(16) char sBuf2[16640];
    ushort_t* sP   = (ushort_t*)sBuf2;           // swizzled [64][64] bf16
    float*    sOut = (float*)sBuf2;              // [16][260] f32 (alias, post-GEMM)

    const int tid  = threadIdx.x;
    const int wave = tid >> 6, lane = tid & 63;
    const int ln   = lane & 15, qd = lane >> 4;
    const int nq   = wave;
    const int token0 = (blockIdx.x >> 1) * 64;
    const int nh = (blockIdx.x & 1) * 256;

    // stage P tile (swizzled, async)
    #pragma unroll
    for (int r = 0; r < 2; r++) {
        int sl = r * 256 + tid;
        int t = sl >> 3, k8 = (sl & 7) ^ (t & 7);
        gload16(P + (size_t)(token0 + t) * 64 + k8 * 8,
                sBuf2 + r * 4096 + wave * 1024);
    }
    __syncthreads();

    floatx4 acc[4][4] = {};
    #pragma unroll
    for (int ks8 = 0; ks8 < 8; ks8 += 4) {
        shortx8 af[4], bf[4];
        #pragma unroll
        for (int mt = 0; mt < 4; mt++) {
            int t = mt * 16 + ln;
            af[mt] = *(const shortx8*)&sP[t * 64 + (((ks8 + qd) ^ (ln & 7)) << 3)];
        }
        #pragma unroll
        for (int nt = 0; nt < 4; nt++) {
            int d = nh + nq * 64 + nt * 16 + ln;
            bf[nt] = *(const shortx8*)(woutb + (size_t)d * 64 + (ks8 + qd) * 8);
        }
        #pragma unroll
        for (int mt = 0; mt < 4; mt++)
            #pragma unroll
            for (int nt = 0; nt < 4; nt++)
                acc[mt][nt] = __builtin_amdgcn_mfma_f32_16x16x32_bf16(
                    af[mt], bf[nt], acc[mt][nt], 0, 0, 0);
    }

    // transposed epilogue, float4 coalesced
    for (int mt = 0; mt < 4; mt++) {
        __syncthreads();                          // mt=0: also guards sP -> sOut alias
        #pragma unroll
        for (int nt = 0; nt < 4; nt++)
            #pragma unroll
            for (int r = 0; r < 4; r++)
                sOut[(qd * 4 + r) * 260 + nq * 64 + nt * 16 + ln] = acc[mt][nt][r];
        __syncthreads();
        #pragma unroll
        for (int i = 0; i < 4; i++) {
            int idx = i * 256 + tid;
            int row = idx >> 6, c4 = (idx & 63) * 4;
            int tok = token0 + mt * 16 + row;
            int d   = nh + c4;
            float4 o  = *(float4*)&sOut[row * 260 + c4];
            float4 xv = *(const float4*)(x + (size_t)tok * DD + d);
            float4 bo = *(const float4*)(bout + d);
            float4 dp = *(const float4*)(Dp + d);
            float4 res;
            res.x = fmaf(fminf(fmaxf(dp.x, -2.f), 2.f), xv.x, o.x + bo.x);
            res.y = fmaf(fminf(fmaxf(dp.y, -2.f), 2.f), xv.y, o.y + bo.y);
            res.z = fmaf(fminf(fmaxf(dp.z, -2.f), 2.f), xv.z, o.z + bo.z);
            res.w = fmaf(fminf(fmaxf(dp.w, -2.f), 2.f), xv.w, o.w + bo.w);
            *(float4*)(out + (size_t)tok * DD + d) = res;
        }
    }
}

// ---------- launch ----------
extern "C" void kernel_launch(void* const* d_in, const int* in_sizes, int n_in,
                              void* d_out, int out_size, void* d_ws, size_t ws_size,
                              hipStream_t stream)
{
    const float* x     = (const float*)d_in[0];
    const float* lnw   = (const float*)d_in[1];
    const float* lnb   = (const float*)d_in[2];
    const float* Wx    = (const float*)d_in[3];
    const float* bx_   = (const float*)d_in[4];
    const float* Wdt   = (const float*)d_in[5];
    const float* bdt   = (const float*)d_in[6];
    const float* A_log = (const float*)d_in[7];
    const float* WB    = (const float*)d_in[8];
    const float* WC    = (const float*)d_in[9];
    const float* Dp    = (const float*)d_in[10];
    const float* Wout  = (const float*)d_in[11];
    const float* bout  = (const float*)d_in[12];
    float* out = (float*)d_out;

    char* w = (char*)d_ws;
    constexpr size_t SZ_XN = (size_t)NTOK * DD * 2;      // 67.1 MB bf16 x_norm
    constexpr size_t SZ_T  = (size_t)NTOK * 64 * 4;      // 16.8 MB per (tok,s) f32
    ushort_t* xn    = (ushort_t*)(w);
    ushort_t* Pm    = (ushort_t*)(w);                    // alias: P live after xn dead
    float*    Ap    = (float*)(w + SZ_XN);
    float*    BXv   = (float*)(w + SZ_XN + SZ_T);
    float*    Ct    = (float*)(w + SZ_XN + 2 * SZ_T);
    float*    Asum  = (float*)(w + SZ_XN + 3 * SZ_T);
    float*    Bsum  = (float*)(w + SZ_XN + 3 * SZ_T + 262144);
    ushort_t* Wcat  = (ushort_t*)(w + SZ_XN + 3 * SZ_T + 2 * 262144);
    ushort_t* WoutB = (ushort_t*)(w + SZ_XN + 3 * SZ_T + 2 * 262144 + 262144);

    k_prep<<<512, 256, 0, stream>>>(Wdt, WB, WC, Wx, Wout, Wcat, WoutB);
    k_ln<<<NTOK / 4, 256, 0, stream>>>(x, lnw, lnb, xn);
    k_proj<<<NTOK / 128, 512, 0, stream>>>(xn, Wcat, bdt, bx_, A_log,
                                           Ap, BXv, Ct, Asum, Bsum);
    k_scan<<<BB * 16, 256, 0, stream>>>(Ap, BXv, Ct, Asum, Bsum, Pm);
    k_gemm2<<<(NTOK / 64) * 2, 256, 0, stream>>>(Pm, WoutB, bout, Dp, x, out);
}